// Round 12
// baseline (225.903 us; speedup 1.0000x reference)
//
#include <hip/hip_runtime.h>
#include <math.h>
#include <float.h>

// DeepSeek V3 router, round 12.
// Diagnosis R6/R7/R9/R11: MfmaUtil pinned at ~27-28% across every occupancy/
// shape/prefetch variant = the 2-phase barrier-per-K-step structural constant
// (catalog m233). Escape: BARRIER-FREE wave-independent GEMM.
//  - wave-tile 32 rows x 256 cols (full E) -> X read once globally, no
//    cross-wave sharing -> no LDS, no barriers, no drains.
//  - A fragments (32x32x16) loaded straight from fp32 X: lane l reads 32B
//    contiguous of row l&31 (4x dwordx4 tile each row's 128B line exactly),
//    converted in-register to a0 / a1*S6 / a0*S5 (validated ops, hoisted).
//  - B global->reg from fragment-packed planes (validated R9), splitK=8,
//    ks = XCD -> 0.92MB L2-resident slice per XCD. 2-group B double-buffer.
// Numerics (validated R7-R11, per-acc op order identical):
//   pass1 a0*b0; pass2 (a1*2^-6)*(b0*2^-5); pass3 (a0*2^-5)*b3
//   a0=fp16(x), a1=fp16(res_x*2048), b0=fp16(256w), b3=fp16(res_w256*32);
//   logit = acc/256.

#define TDIM 8192
#define DDIM 7168
#define EDIM 256
#define KT   (DDIM / 32)   // 224 k-tiles of 32

typedef _Float16 h8 __attribute__((ext_vector_type(8)));
typedef float f16v __attribute__((ext_vector_type(16)));

// ---------------- K1: W -> 32x32x16-fragment-packed fp16 planes ------------
// Record (p, cf, ktl, kf) at halfs-offset (((p*8+cf)*KT+ktl)*2+kf)*512+lane*8
// with lane = (e&31) + 32*((k>>3)&1)  [validated R9-R11].
__global__ __launch_bounds__(256)
void convert_w(const float* __restrict__ W, _Float16* __restrict__ Bp)
{
    __shared__ _Float16 l0[64][80];
    __shared__ _Float16 l1[64][80];
    const int t = threadIdx.x;
    const int kt = blockIdx.x * 64;
    const int et = blockIdx.y * 64;
#pragma unroll
    for (int i = 0; i < 16; ++i) {
        const int kr = (t >> 6) * 16 + i;
        const int ec = t & 63;
        const float w = W[(size_t)(kt + kr) * EDIM + et + ec] * 256.f;
        const _Float16 h0 = (_Float16)w;
        const _Float16 h1 = (_Float16)((w - (float)h0) * 32.f);
        l0[ec][kr] = h0;
        l1[ec][kr] = h1;
    }
    __syncthreads();
#pragma unroll
    for (int j = 0; j < 2; ++j) {
        const int er = t >> 2;
        const int kc = ((t & 3) + 4 * j) * 8;
        const int e  = et + er;
        const int k  = kt + kc;
        const int cf   = e >> 5;
        const int lane = (e & 31) + 32 * ((k >> 3) & 1);
        const int kf   = (k >> 4) & 1;
        const int ktl  = k >> 5;
        const uint4 v0 = *(const uint4*)&l0[er][kc];
        const uint4 v1 = *(const uint4*)&l1[er][kc];
        const size_t o0 = (((size_t)(0 * 8 + cf) * KT + ktl) * 2 + kf) * 512 + lane * 8;
        const size_t o1 = (((size_t)(1 * 8 + cf) * KT + ktl) * 2 + kf) * 512 + lane * 8;
        *(uint4*)&Bp[o0] = v0;
        *(uint4*)&Bp[o1] = v1;
    }
}

// ------- K2: barrier-free 32x32x16 split-fp16 GEMM, all operands -> regs ----
__global__ __launch_bounds__(256, 2)
void gemm_mfma(const float* __restrict__ X,
               const _Float16* __restrict__ Bp,
               float* __restrict__ P,
               int splitK, int kLen)
{
    const int t    = threadIdx.x;
    const int lane = t & 63;
    const int w    = t >> 6;

    // worker mapping: ks tied to XCD (bid&7) for L2 slice residency.
    const int bid  = blockIdx.x;
    const int ks   = (bid & 7) % splitK;
    const int mgrp = (bid >> 3) * (8 / splitK) + (bid & 7) / splitK;
    const int mb   = mgrp * 4 + w;          // 0..255 row-tile of 32
    const int m0   = mb * 32;
    const int kbeg = ks * kLen;
    const int nt   = kLen >> 5;
    const int ktg0 = kbeg >> 5;

    f16v acc[8];
#pragma unroll
    for (int n = 0; n < 8; ++n) acc[n] = (f16v)0.f;

    // A source: lane l -> row m0+(l&31), k base (l>>5)*8 within the tile
    const float* xrow =
        X + (size_t)(m0 + (lane & 31)) * DDIM + kbeg + (lane >> 5) * 8;
    const _Float16* bb = Bp + lane * 8;

    const _Float16 S5 = (_Float16)0.03125f;    // 2^-5
    const _Float16 S6 = (_Float16)0.015625f;   // 2^-6

    float4 xs0, xs1, xs2, xs3;          // staged fp32 X (kf0: xs0/1, kf1: xs2/3)
    h8 a0[2], a0s[2], a1s[2];           // per-kf fragments
    h8 bA[2][2][2], bB[2][2][2];        // [n-local][plane][kf] groups

#define LOADX(kb)                                                             \
    {                                                                         \
        xs0 = *(const float4*)(xrow + (kb));                                  \
        xs1 = *(const float4*)(xrow + (kb) + 4);                              \
        xs2 = *(const float4*)(xrow + (kb) + 16);                             \
        xs3 = *(const float4*)(xrow + (kb) + 20);                             \
    }

#define CONVA()                                                               \
    {                                                                         \
        const float xv[16] = {xs0.x, xs0.y, xs0.z, xs0.w,                     \
                              xs1.x, xs1.y, xs1.z, xs1.w,                     \
                              xs2.x, xs2.y, xs2.z, xs2.w,                     \
                              xs3.x, xs3.y, xs3.z, xs3.w};                    \
        _Pragma("unroll")                                                     \
        for (int kf = 0; kf < 2; ++kf) {                                      \
            h8 p0, p1;                                                        \
            _Pragma("unroll")                                                 \
            for (int q = 0; q < 8; ++q) {                                     \
                const float xq = xv[kf * 8 + q];                              \
                const _Float16 h0 = (_Float16)xq;                             \
                p0[q] = h0;                                                   \
                p1[q] = (_Float16)((xq - (float)h0) * 2048.f);                \
            }                                                                 \
            a0[kf] = p0;                                                      \
            _Pragma("unroll")                                                 \
            for (int q = 0; q < 8; ++q) { p1[q] *= S6; }                      \
            a1s[kf] = p1;                                                     \
            h8 ps = p0;                                                       \
            _Pragma("unroll")                                                 \
            for (int q = 0; q < 8; ++q) { ps[q] *= S5; }                      \
            a0s[kf] = ps;                                                     \
        }                                                                     \
    }

    // load B group g (n = 2g, 2g+1) of tile TI into RB
#define LOADB(RB, g, TI)                                                      \
    {                                                                         \
        _Pragma("unroll")                                                     \
        for (int p = 0; p < 2; ++p)                                           \
        _Pragma("unroll")                                                     \
        for (int nn = 0; nn < 2; ++nn)                                        \
        _Pragma("unroll")                                                     \
        for (int kf = 0; kf < 2; ++kf)                                        \
            RB[nn][p][kf] = *(const h8*)(bb +                                 \
                (((size_t)(p * 8 + 2 * (g) + nn) * KT + (TI)) * 2 + kf) * 512); \
    }

    // 12 MFMAs of group g (acc 2g, 2g+1), validated per-acc order
#define MFMAG(RB, g)                                                          \
    {                                                                         \
        _Pragma("unroll")                                                     \
        for (int kf = 0; kf < 2; ++kf)                                        \
        _Pragma("unroll")                                                     \
        for (int nn = 0; nn < 2; ++nn)                                        \
            acc[2 * (g) + nn] = __builtin_amdgcn_mfma_f32_32x32x16_f16(       \
                a0[kf], RB[nn][0][kf], acc[2 * (g) + nn], 0, 0, 0);           \
        _Pragma("unroll")                                                     \
        for (int nn = 0; nn < 2; ++nn)                                        \
        _Pragma("unroll")                                                     \
        for (int kf = 0; kf < 2; ++kf)                                        \
        _Pragma("unroll")                                                     \
        for (int q = 0; q < 8; ++q) RB[nn][0][kf][q] *= S5;                   \
        _Pragma("unroll")                                                     \
        for (int kf = 0; kf < 2; ++kf)                                        \
        _Pragma("unroll")                                                     \
        for (int nn = 0; nn < 2; ++nn)                                        \
            acc[2 * (g) + nn] = __builtin_amdgcn_mfma_f32_32x32x16_f16(       \
                a1s[kf], RB[nn][0][kf], acc[2 * (g) + nn], 0, 0, 0);          \
        _Pragma("unroll")                                                     \
        for (int kf = 0; kf < 2; ++kf)                                        \
        _Pragma("unroll")                                                     \
        for (int nn = 0; nn < 2; ++nn)                                        \
            acc[2 * (g) + nn] = __builtin_amdgcn_mfma_f32_32x32x16_f16(       \
                a0s[kf], RB[nn][1][kf], acc[2 * (g) + nn], 0, 0, 0);          \
    }

    // ---- prologue ----
    LOADX(0);
    LOADB(bA, 0, ktg0);
    CONVA();

    for (int ti = 0; ti < nt; ++ti) {
        const int TI = ktg0 + ti;
        const bool hn = (ti + 1) < nt;
        if (hn) LOADX((ti + 1) * 32);

        LOADB(bB, 1, TI);
        MFMAG(bA, 0);
        LOADB(bA, 2, TI);
        MFMAG(bB, 1);
        LOADB(bB, 3, TI);
        MFMAG(bA, 2);
        if (hn) LOADB(bA, 0, TI + 1);
        MFMAG(bB, 3);

        if (hn) CONVA();    // consumes xs for tile ti+1 (loaded above)
    }

    // epilogue: logit = acc/256; C/D col=lane&31, row=(r&3)+8*(r>>2)+4*(lane>>5)
    const float s0 = 1.f / 256.f;
#pragma unroll
    for (int n = 0; n < 8; ++n)
#pragma unroll
        for (int r = 0; r < 16; ++r) {
            const int row = (r & 3) + 8 * (r >> 2) + 4 * (lane >> 5);
            const int gr  = m0 + row;
            const int gc  = n * 32 + (lane & 31);
            P[((size_t)ks * TDIM + gr) * EDIM + gc] = acc[n][r] * s0;
        }
}

// ---------------- K3: reduce + sigmoid + grouped top-k route ----------------
__global__ __launch_bounds__(256, 4)
void route_kernel(const float* __restrict__ P,
                  const float* __restrict__ B,
                  float* __restrict__ out,
                  int splitK)
{
    const int t    = threadIdx.x;
    const int lane = t & 63;
    const int wid  = t >> 6;
    const int tok0 = blockIdx.x * 32 + wid * 8;

    const float4 bv4 = *(const float4*)&B[lane * 4];
    const float bb[4] = {bv4.x, bv4.y, bv4.z, bv4.w};
    const int g = lane >> 3;

#pragma unroll
    for (int i = 0; i < 8; ++i) {
        const int tok = tok0 + i;
        float a[4] = {0.f, 0.f, 0.f, 0.f};
        for (int ksl = 0; ksl < splitK; ++ksl) {
            const float4 pv =
                *(const float4*)&P[((size_t)ksl * TDIM + tok) * EDIM + lane * 4];
            a[0] += pv.x; a[1] += pv.y; a[2] += pv.z; a[3] += pv.w;
        }
        float v[4], s[4];
#pragma unroll
        for (int jq = 0; jq < 4; ++jq) {
            v[jq] = 1.f / (1.f + expf(-a[jq]));
            s[jq] = v[jq] + bb[jq];
        }
        float t1 = s[0], t2 = -FLT_MAX;
#pragma unroll
        for (int jq = 1; jq < 4; ++jq) {
            if (s[jq] > t1) { t2 = t1; t1 = s[jq]; }
            else if (s[jq] > t2) t2 = s[jq];
        }
#pragma unroll
        for (int d = 1; d < 8; d <<= 1) {
            float o1 = __shfl_xor(t1, d);
            float o2 = __shfl_xor(t2, d);
            float n1 = fmaxf(t1, o1);
            float n2 = fmaxf(fminf(t1, o1), fmaxf(t2, o2));
            t1 = n1; t2 = n2;
        }
        const float gsc = t1 + t2;
        float gs[8];
#pragma unroll
        for (int q = 0; q < 8; ++q) gs[q] = __shfl(gsc, q * 8);
        int gmask = 0;
#pragma unroll
        for (int it = 0; it < 4; ++it) {
            float bvv = -FLT_MAX; int bg = 0;
#pragma unroll
            for (int q = 0; q < 8; ++q) {
                const bool avail = ((gmask >> q) & 1) == 0;
                if (avail && gs[q] > bvv) { bvv = gs[q]; bg = q; }
            }
            gmask |= (1 << bg);
        }
        if (((gmask >> g) & 1) == 0) { s[0] = 0.f; s[1] = 0.f; s[2] = 0.f; s[3] = 0.f; }

        float wk[8]; int ik[8]; float wsum = 0.f;
#pragma unroll
        for (int it = 0; it < 8; ++it) {
            float bvv = s[0]; int bi = lane * 4; float bs = v[0];
#pragma unroll
            for (int jq = 1; jq < 4; ++jq)
                if (s[jq] > bvv) { bvv = s[jq]; bi = lane * 4 + jq; bs = v[jq]; }
#pragma unroll
            for (int d = 1; d < 64; d <<= 1) {
                float ov = __shfl_xor(bvv, d);
                int   oi = __shfl_xor(bi, d);
                float os = __shfl_xor(bs, d);
                if (ov > bvv || (ov == bvv && oi < bi)) { bvv = ov; bi = oi; bs = os; }
            }
            wk[it] = bs; ik[it] = bi; wsum += bs;
#pragma unroll
            for (int jq = 0; jq < 4; ++jq)
                if (bi == lane * 4 + jq) s[jq] = -FLT_MAX;
        }
        const float den = wsum + 1e-20f;
        if (lane == 0) {
#pragma unroll
            for (int q = 0; q < 8; ++q) {
                out[(size_t)tok * 8 + q] = wk[q] / den * 2.5f;
                out[(size_t)TDIM * 8 + (size_t)tok * 8 + q] = (float)ik[q];
            }
        }
    }
}

extern "C" void kernel_launch(void* const* d_in, const int* in_sizes, int n_in,
                              void* d_out, int out_size, void* d_ws, size_t ws_size,
                              hipStream_t stream)
{
    (void)in_sizes; (void)n_in; (void)out_size;
    const float* x    = (const float*)d_in[0];
    const float* kern = (const float*)d_in[1];
    const float* bias = (const float*)d_in[2];
    float* out = (float*)d_out;

    const size_t packedBytes = (size_t)2 * 8 * KT * 2 * 512 * 2;   // 7.34 MB
    int splitK = 8;
    while (splitK > 1 &&
           (size_t)splitK * TDIM * EDIM * 4 + packedBytes > ws_size)
        splitK >>= 1;

    float* P = (float*)d_ws;
    _Float16* Bp = (_Float16*)((char*)d_ws + (size_t)splitK * TDIM * EDIM * 4);

    convert_w<<<dim3(DDIM / 64, EDIM / 64), 256, 0, stream>>>(kern, Bp);
    gemm_mfma<<<64 * splitK, 256, 0, stream>>>(
        x, Bp, P, splitK, DDIM / splitK);
    route_kernel<<<TDIM / 32, 256, 0, stream>>>(P, bias, out, splitK);
}

// Round 13
// 162.073 us; speedup vs baseline: 1.3938x; 1.3938x over previous
//
#include <hip/hip_runtime.h>
#include <math.h>
#include <float.h>

// DeepSeek V3 router, round 13.
// Ledger: R6/R7/R9/R11 all pin MfmaUtil ~28% in the 2-phase barrier-per-K-step
// structure (catalog m233's constant). R12's barrier-free variant was VMEM-
// bound (4x B traffic). This round ports the catalog's measured escape
// (T3+T4+T5: fine-grained phase interleave, barrier pairs, counted waits,
// setprio) onto the validated R9/R11 data paths:
//   block 64Mx256N, 4 waves, wave-tile 64x64; A via XOR-swizzled LDS
//   (2-way max both sides); B global->reg from fragment-packed L2 planes.
//   K-step = 64k = 4 phases; per phase: {AREAD chunk q || 1/4 X-stage} ->
//   barrier -> lgkm0+sched_barrier -> 12 MFMA (setprio) -> B reload -> barrier.
//   X staged 2 steps deep (load in step s-1, write in step s for step s+1);
//   B chunks rotate 2 phases ahead; all loads compiler-counted, never drained.
// Numerics (validated R7-R12): pass1 a0*b0; pass2 (a1*2^-6)*(b0*2^-5);
// pass3 (a0*2^-5)*b3; logit = acc/256.

#define TDIM 8192
#define DDIM 7168
#define EDIM 256
#define KT   (DDIM / 32)   // 224 k-tiles of 32

typedef _Float16 h8 __attribute__((ext_vector_type(8)));
typedef float f16v __attribute__((ext_vector_type(16)));

// ---------------- K1: W -> 32x32x16-fragment-packed fp16 planes ------------
// Offset(halfs) = ((p*8+cf)*448 + K16)*512 + lane*8, lane=(e&31)+32*((k>>3)&1)
__global__ __launch_bounds__(256)
void convert_w(const float* __restrict__ W, _Float16* __restrict__ Bp)
{
    __shared__ _Float16 l0[64][80];
    __shared__ _Float16 l1[64][80];
    const int t = threadIdx.x;
    const int kt = blockIdx.x * 64;
    const int et = blockIdx.y * 64;
#pragma unroll
    for (int i = 0; i < 16; ++i) {
        const int kr = (t >> 6) * 16 + i;
        const int ec = t & 63;
        const float w = W[(size_t)(kt + kr) * EDIM + et + ec] * 256.f;
        const _Float16 h0 = (_Float16)w;
        const _Float16 h1 = (_Float16)((w - (float)h0) * 32.f);
        l0[ec][kr] = h0;
        l1[ec][kr] = h1;
    }
    __syncthreads();
#pragma unroll
    for (int j = 0; j < 2; ++j) {
        const int er = t >> 2;
        const int kc = ((t & 3) + 4 * j) * 8;
        const int e  = et + er;
        const int k  = kt + kc;
        const int cf   = e >> 5;
        const int lane = (e & 31) + 32 * ((k >> 3) & 1);
        const int kf   = (k >> 4) & 1;
        const int ktl  = k >> 5;
        const uint4 v0 = *(const uint4*)&l0[er][kc];
        const uint4 v1 = *(const uint4*)&l1[er][kc];
        const size_t o0 = (((size_t)(0 * 8 + cf) * KT + ktl) * 2 + kf) * 512 + lane * 8;
        const size_t o1 = (((size_t)(1 * 8 + cf) * KT + ktl) * 2 + kf) * 512 + lane * 8;
        *(uint4*)&Bp[o0] = v0;
        *(uint4*)&Bp[o1] = v1;
    }
}

// ---- K2: 4-phase-per-K64 split-fp16 GEMM (A LDS-swizzled, B from L2) ------
__global__ __launch_bounds__(256, 2)
void gemm_mfma(const float* __restrict__ X,
               const _Float16* __restrict__ Bp,
               float* __restrict__ P,
               int splitK, int kLen)
{
    __shared__ _Float16 sA[2][2][64][64];   // [buf][plane][row][halfs], 64 KB

    const int t    = threadIdx.x;
    const int lane = t & 63;
    const int w    = t >> 6;                // wave -> n-quadrant w*64

    const int bid  = blockIdx.x;
    const int ks   = (bid & 7) % splitK;
    const int mb   = (bid >> 3) * (8 / splitK) + (bid & 7) / splitK;
    const int m0   = mb * 64;
    const int kbeg = ks * kLen;
    const int nsteps = kLen >> 6;           // 28 (even)
    const int k16b   = kbeg >> 4;

    f16v acc[2][2];
#pragma unroll
    for (int m = 0; m < 2; ++m)
#pragma unroll
        for (int n = 0; n < 2; ++n) acc[m][n] = (f16v)0.f;

    // X staging: thread -> row srow(+32/piece), 8 floats at scol (256B/8 lanes)
    const int srow = t >> 3;                // 0..31
    const int sg   = t & 7;                 // raw 16B granule
    const float* xg = X + (size_t)(m0 + srow) * DDIM + kbeg + sg * 8;

    const _Float16* bb = Bp + lane * 8;

    const _Float16 S5 = (_Float16)0.03125f;     // 2^-5
    const _Float16 S6 = (_Float16)0.015625f;    // 2^-6

#define AREAD(CUR, Q)                                                         \
    {                                                                         \
        _Pragma("unroll")                                                     \
        for (int m = 0; m < 2; ++m) {                                         \
            const int rr = m * 32 + (lane & 31);                              \
            const int gq = ((((Q) * 2 + (lane >> 5)) ^ (rr & 7))) * 8;        \
            a0[m] = *(const h8*)&sA[CUR][0][rr][gq];                          \
            a1[m] = *(const h8*)&sA[CUR][1][rr][gq];                          \
        }                                                                     \
    }

#define BLOADQ(RB, K16)                                                       \
    {                                                                         \
        _Pragma("unroll")                                                     \
        for (int p = 0; p < 2; ++p)                                           \
        _Pragma("unroll")                                                     \
        for (int n = 0; n < 2; ++n)                                           \
            RB[n][p] = *(const h8*)(bb +                                      \
                ((size_t)(p * 8 + w * 2 + n) * (2 * KT) + (K16)) * 512);      \
    }

#define LOADX2(R0, R1, PIECE, S)                                              \
    {                                                                         \
        const float* xp = xg + (size_t)(PIECE) * 32 * DDIM + (S) * 64;        \
        R0 = *(const float4*)(xp);                                            \
        R1 = *(const float4*)(xp + 4);                                        \
    }

#define CONVW(BUF, PIECE, R0, R1)                                             \
    {                                                                         \
        h8 p0, p1;                                                            \
        const float xv[8] = {R0.x, R0.y, R0.z, R0.w, R1.x, R1.y, R1.z, R1.w}; \
        _Pragma("unroll")                                                     \
        for (int q = 0; q < 8; ++q) {                                         \
            const _Float16 h0 = (_Float16)xv[q];                              \
            p0[q] = h0;                                                       \
            p1[q] = (_Float16)((xv[q] - (float)h0) * 2048.f);                 \
        }                                                                     \
        const int r  = srow + 32 * (PIECE);                                   \
        const int gq = (sg ^ (r & 7)) * 8;                                    \
        *(h8*)&sA[BUF][0][r][gq] = p0;                                        \
        *(h8*)&sA[BUF][1][r][gq] = p1;                                        \
    }

#define MFMAQ(RB)                                                             \
    {                                                                         \
        __builtin_amdgcn_s_setprio(1);                                        \
        _Pragma("unroll")                                                     \
        for (int m = 0; m < 2; ++m)                                           \
        _Pragma("unroll")                                                     \
        for (int n = 0; n < 2; ++n)                                           \
            acc[m][n] = __builtin_amdgcn_mfma_f32_32x32x16_f16(               \
                a0[m], RB[n][0], acc[m][n], 0, 0, 0);                         \
        _Pragma("unroll")                                                     \
        for (int n = 0; n < 2; ++n)                                           \
        _Pragma("unroll")                                                     \
        for (int q = 0; q < 8; ++q) RB[n][0][q] *= S5;                        \
        _Pragma("unroll")                                                     \
        for (int m = 0; m < 2; ++m)                                           \
        _Pragma("unroll")                                                     \
        for (int q = 0; q < 8; ++q) a1[m][q] *= S6;                           \
        _Pragma("unroll")                                                     \
        for (int m = 0; m < 2; ++m)                                           \
        _Pragma("unroll")                                                     \
        for (int n = 0; n < 2; ++n)                                           \
            acc[m][n] = __builtin_amdgcn_mfma_f32_32x32x16_f16(               \
                a1[m], RB[n][0], acc[m][n], 0, 0, 0);                         \
        _Pragma("unroll")                                                     \
        for (int m = 0; m < 2; ++m)                                           \
        _Pragma("unroll")                                                     \
        for (int q = 0; q < 8; ++q) a0[m][q] *= S5;                           \
        _Pragma("unroll")                                                     \
        for (int m = 0; m < 2; ++m)                                           \
        _Pragma("unroll")                                                     \
        for (int n = 0; n < 2; ++n)                                           \
            acc[m][n] = __builtin_amdgcn_mfma_f32_32x32x16_f16(               \
                a0[m], RB[n][1], acc[m][n], 0, 0, 0);                         \
        __builtin_amdgcn_s_setprio(0);                                        \
    }

#define PHASE(CUR, Q, RB, STG, BNX)                                           \
    {                                                                         \
        h8 a0[2], a1[2];                                                      \
        AREAD(CUR, Q);                                                        \
        STG;                                                                  \
        __builtin_amdgcn_s_barrier();                                         \
        asm volatile("s_waitcnt lgkmcnt(0)" ::: "memory");                    \
        __builtin_amdgcn_sched_barrier(0);                                    \
        MFMAQ(RB);                                                            \
        BNX;                                                                  \
        __builtin_amdgcn_s_barrier();                                         \
    }

    // STEP: reads sA[CUR]; loads X(step S+2) into L*, writes X(step S+1)
    // from W* into sA[CUR^1]; B chunks rotate 2 phases ahead.
#define STEP_BODY(S, CUR, L0, L1, L2, L3, W0, W1, W2, W3)                     \
    {                                                                         \
        const int kk = k16b + (S) * 4;                                        \
        const bool h1 = (S) + 1 < nsteps;                                     \
        const bool h2 = (S) + 2 < nsteps;                                     \
        PHASE(CUR, 0, bBuf0,                                                  \
              { if (h2) LOADX2(L0, L1, 0, (S) + 2); },                        \
              { BLOADQ(bBuf0, kk + 2); });                                    \
        PHASE(CUR, 1, bBuf1,                                                  \
              { if (h1) CONVW((CUR) ^ 1, 0, W0, W1); },                       \
              { BLOADQ(bBuf1, kk + 3); });                                    \
        PHASE(CUR, 2, bBuf0,                                                  \
              { if (h2) LOADX2(L2, L3, 1, (S) + 2); },                        \
              { if (h1) BLOADQ(bBuf0, kk + 4); });                            \
        PHASE(CUR, 3, bBuf1,                                                  \
              { if (h1) CONVW((CUR) ^ 1, 1, W2, W3); },                       \
              { if (h1) BLOADQ(bBuf1, kk + 5); });                            \
    }

    float4 xA0, xA1, xA2, xA3, xB0, xB1, xB2, xB3;
    h8 bBuf0[2][2], bBuf1[2][2];

    // ---- prologue: stage step 0 into buf0; preload B chunks 0,1; X(step1) ->
    // xB (written during step 0); X(step2) loaded during step 0 into xA.
    LOADX2(xA0, xA1, 0, 0);
    LOADX2(xA2, xA3, 1, 0);
    BLOADQ(bBuf0, k16b + 0);
    BLOADQ(bBuf1, k16b + 1);
    CONVW(0, 0, xA0, xA1);
    CONVW(0, 1, xA2, xA3);
    if (nsteps > 1) { LOADX2(xB0, xB1, 0, 1); LOADX2(xB2, xB3, 1, 1); }
    asm volatile("s_waitcnt lgkmcnt(0)" ::: "memory");
    __builtin_amdgcn_s_barrier();

    for (int s = 0; s < nsteps; s += 2) {
        STEP_BODY(s,     0, xA0, xA1, xA2, xA3, xB0, xB1, xB2, xB3);
        STEP_BODY(s + 1, 1, xB0, xB1, xB2, xB3, xA0, xA1, xA2, xA3);
    }

    // epilogue: logit = acc/256; C/D col=lane&31, row=(r&3)+8*(r>>2)+4*(lane>>5)
    const float s0 = 1.f / 256.f;
#pragma unroll
    for (int m = 0; m < 2; ++m)
#pragma unroll
        for (int n = 0; n < 2; ++n)
#pragma unroll
            for (int r = 0; r < 16; ++r) {
                const int row = (r & 3) + 8 * (r >> 2) + 4 * (lane >> 5);
                const int gr  = m0 + m * 32 + row;
                const int gc  = w * 64 + n * 32 + (lane & 31);
                P[((size_t)ks * TDIM + gr) * EDIM + gc] = acc[m][n][r] * s0;
            }
}

// ---------------- K3: reduce + sigmoid + grouped top-k route ----------------
__global__ __launch_bounds__(256, 4)
void route_kernel(const float* __restrict__ P,
                  const float* __restrict__ B,
                  float* __restrict__ out,
                  int splitK)
{
    const int t    = threadIdx.x;
    const int lane = t & 63;
    const int wid  = t >> 6;
    const int tok0 = blockIdx.x * 32 + wid * 8;

    const float4 bv4 = *(const float4*)&B[lane * 4];
    const float bb[4] = {bv4.x, bv4.y, bv4.z, bv4.w};
    const int g = lane >> 3;

#pragma unroll
    for (int i = 0; i < 8; ++i) {
        const int tok = tok0 + i;
        float a[4] = {0.f, 0.f, 0.f, 0.f};
        for (int ksl = 0; ksl < splitK; ++ksl) {
            const float4 pv =
                *(const float4*)&P[((size_t)ksl * TDIM + tok) * EDIM + lane * 4];
            a[0] += pv.x; a[1] += pv.y; a[2] += pv.z; a[3] += pv.w;
        }
        float v[4], s[4];
#pragma unroll
        for (int jq = 0; jq < 4; ++jq) {
            v[jq] = 1.f / (1.f + expf(-a[jq]));
            s[jq] = v[jq] + bb[jq];
        }
        float t1 = s[0], t2 = -FLT_MAX;
#pragma unroll
        for (int jq = 1; jq < 4; ++jq) {
            if (s[jq] > t1) { t2 = t1; t1 = s[jq]; }
            else if (s[jq] > t2) t2 = s[jq];
        }
#pragma unroll
        for (int d = 1; d < 8; d <<= 1) {
            float o1 = __shfl_xor(t1, d);
            float o2 = __shfl_xor(t2, d);
            float n1 = fmaxf(t1, o1);
            float n2 = fmaxf(fminf(t1, o1), fmaxf(t2, o2));
            t1 = n1; t2 = n2;
        }
        const float gsc = t1 + t2;
        float gs[8];
#pragma unroll
        for (int q = 0; q < 8; ++q) gs[q] = __shfl(gsc, q * 8);
        int gmask = 0;
#pragma unroll
        for (int it = 0; it < 4; ++it) {
            float bvv = -FLT_MAX; int bg = 0;
#pragma unroll
            for (int q = 0; q < 8; ++q) {
                const bool avail = ((gmask >> q) & 1) == 0;
                if (avail && gs[q] > bvv) { bvv = gs[q]; bg = q; }
            }
            gmask |= (1 << bg);
        }
        if (((gmask >> g) & 1) == 0) { s[0] = 0.f; s[1] = 0.f; s[2] = 0.f; s[3] = 0.f; }

        float wk[8]; int ik[8]; float wsum = 0.f;
#pragma unroll
        for (int it = 0; it < 8; ++it) {
            float bvv = s[0]; int bi = lane * 4; float bs = v[0];
#pragma unroll
            for (int jq = 1; jq < 4; ++jq)
                if (s[jq] > bvv) { bvv = s[jq]; bi = lane * 4 + jq; bs = v[jq]; }
#pragma unroll
            for (int d = 1; d < 64; d <<= 1) {
                float ov = __shfl_xor(bvv, d);
                int   oi = __shfl_xor(bi, d);
                float os = __shfl_xor(bs, d);
                if (ov > bvv || (ov == bvv && oi < bi)) { bvv = ov; bi = oi; bs = os; }
            }
            wk[it] = bs; ik[it] = bi; wsum += bs;
#pragma unroll
            for (int jq = 0; jq < 4; ++jq)
                if (bi == lane * 4 + jq) s[jq] = -FLT_MAX;
        }
        const float den = wsum + 1e-20f;
        if (lane == 0) {
#pragma unroll
            for (int q = 0; q < 8; ++q) {
                out[(size_t)tok * 8 + q] = wk[q] / den * 2.5f;
                out[(size_t)TDIM * 8 + (size_t)tok * 8 + q] = (float)ik[q];
            }
        }
    }
}

extern "C" void kernel_launch(void* const* d_in, const int* in_sizes, int n_in,
                              void* d_out, int out_size, void* d_ws, size_t ws_size,
                              hipStream_t stream)
{
    (void)in_sizes; (void)n_in; (void)out_size;
    const float* x    = (const float*)d_in[0];
    const float* kern = (const float*)d_in[1];
    const float* bias = (const float*)d_in[2];
    float* out = (float*)d_out;

    const size_t packedBytes = (size_t)2 * 8 * KT * 2 * 512 * 2;   // 7.34 MB
    int splitK = 4;
    while (splitK > 1 &&
           (size_t)splitK * TDIM * EDIM * 4 + packedBytes > ws_size)
        splitK >>= 1;

    float* P = (float*)d_ws;
    _Float16* Bp = (_Float16*)((char*)d_ws + (size_t)splitK * TDIM * EDIM * 4);

    convert_w<<<dim3(DDIM / 64, EDIM / 64), 256, 0, stream>>>(kern, Bp);
    gemm_mfma<<<(TDIM / 64) * splitK, 256, 0, stream>>>(
        x, Bp, P, splitK, DDIM / splitK);
    route_kernel<<<TDIM / 32, 256, 0, stream>>>(P, bias, out, splitK);
}